// Round 6
// baseline (109.392 us; speedup 1.0000x reference)
//
#include <hip/hip_runtime.h>
#include <stdint.h>

// minerva2: echo = (F̂ Ê^T)^3 @ V, intensity = rowsum((F̂ Ê^T)^3)
// R6 = R5 body + T3/T4 counted-vmcnt pipeline: 4 slab buffers (16KB each),
// issue-ahead=2, s_waitcnt vmcnt(8) + raw s_barrier per step (no vmcnt(0)
// drains in steady state). Stash aliases buf3 during PV. T5 setprio on MFMA.

typedef unsigned short u16;
typedef __bf16 bf16x8 __attribute__((ext_vector_type(8)));
typedef float f32x4 __attribute__((ext_vector_type(4)));
typedef unsigned short u16x4 __attribute__((ext_vector_type(4)));

#define NQ 8192
#define ND 16384
#define NH 256
#define NC 28
#define DCHUNK 1024
#define NDT 8        // 128-row D-tiles per chunk
#define NSLOT 16     // partial slots = 16 D-chunks

#define VM8 asm volatile("s_waitcnt vmcnt(8)" ::: "memory")
#define VM4 asm volatile("s_waitcnt vmcnt(4)" ::: "memory")
#define VM0 asm volatile("s_waitcnt vmcnt(0)" ::: "memory")
#define SBAR { __builtin_amdgcn_s_barrier(); asm volatile("" ::: "memory"); }

__device__ __forceinline__ u16 f2bf(float f) {
  unsigned u = __builtin_bit_cast(unsigned, f);
  u += 0x7fffu + ((u >> 16) & 1u);   // RNE
  return (u16)(u >> 16);
}

__device__ __forceinline__ void gload16(const void* g, void* l) {
  // async global->LDS, 16B/lane; LDS dest = wave-uniform base + lane*16
  __builtin_amdgcn_global_load_lds(
      (__attribute__((address_space(1))) void*)g,
      (__attribute__((address_space(3))) void*)l, 16, 0, 0);
}

// ---------------- normalize rows of [rows][256] f32 -> bf16 ----------------
__global__ __launch_bounds__(256) void norm_kernel(const float* __restrict__ in,
                                                   u16* __restrict__ out, int rows) {
  const int wid = threadIdx.x >> 6, lane = threadIdx.x & 63;
  const int row = blockIdx.x * 4 + wid;
  if (row >= rows) return;
  const float4* p = (const float4*)(in + (size_t)row * NH);
  float4 v = p[lane];
  float ss = v.x * v.x + v.y * v.y + v.z * v.z + v.w * v.w;
#pragma unroll
  for (int m = 1; m <= 32; m <<= 1) ss += __shfl_xor(ss, m, 64);
  const float sc = 1.0f / fmaxf(sqrtf(ss), 1e-12f);  // matches F.normalize eps
  u16x4 o;
  o.x = f2bf(v.x * sc); o.y = f2bf(v.y * sc);
  o.z = f2bf(v.z * sc); o.w = f2bf(v.w * sc);
  *(u16x4*)(out + (size_t)row * NH + lane * 4) = o;
}

// ---- V [16384][28] f32 -> Vt [32][16384] bf16; col 28 = 1.0 (intensity) ---
__global__ __launch_bounds__(256) void vt_kernel(const float* __restrict__ V,
                                                 u16* __restrict__ Vt) {
  const int d = blockIdx.x * 256 + threadIdx.x;  // 16384
#pragma unroll
  for (int c = 0; c < NC; ++c) Vt[(size_t)c * ND + d] = f2bf(V[(size_t)d * NC + c]);
  Vt[(size_t)28 * ND + d] = 0x3F80;  // bf16 1.0 -> echo col 28 == intensity
  Vt[(size_t)29 * ND + d] = 0;
  Vt[(size_t)30 * ND + d] = 0;
  Vt[(size_t)31 * ND + d] = 0;
}

// ---------------- fused main kernel ----------------------------------------
// grid 1024: dch = bid&15, ntile = bid>>4. 4 waves, 1x4: wave w owns 32 rows.
// Q A-frags in registers. LDS 64KB = 4 slab bufs of 16KB (slab s -> buf s&3).
// Slab s = (tile s>>2, H-cols (s&3)*64). Pipeline: issue-ahead 2, vmcnt(8).
// PV stash aliases buf3 (4KB/wave).
__global__ __launch_bounds__(256, 2) void fused_kernel(
    const u16* __restrict__ Qn, const u16* __restrict__ Kn,
    const u16* __restrict__ Vt, float* __restrict__ ep) {
  __shared__ alignas(16) char smem[65536];
  const int tid = threadIdx.x;
  const int wid = tid >> 6;
  const int lane = tid & 63;
  const int l16 = lane & 15;
  const int lg = lane >> 4;
  const int dch = blockIdx.x & 15;
  const int ntile = blockIdx.x >> 4;
  const int qbase = ntile * 128;
  const int rowbase = qbase + wid * 32;

  // ---- Q fragments, all H, in registers ----
  bf16x8 qA[2][8];
#pragma unroll
  for (int mb = 0; mb < 2; ++mb)
#pragma unroll
    for (int ks = 0; ks < 8; ++ks)
      qA[mb][ks] = *(const bf16x8*)(Qn + (size_t)(rowbase + mb * 16 + l16) * NH +
                                    ks * 32 + lg * 8);

  f32x4 eacc[2][2];
#pragma unroll
  for (int mb = 0; mb < 2; ++mb) {
    eacc[mb][0] = f32x4{0.f, 0.f, 0.f, 0.f};
    eacc[mb][1] = f32x4{0.f, 0.f, 0.f, 0.f};
  }
  f32x4 sacc[2][8];

  // stage a 128-row x 64-col slab (base = slab's first row, first col) to buf.
  // Linear LDS dest; source chunk pre-swizzled: c8 ^= row&7 (rule #21).
  auto stage_to = [&](int buf, const u16* kslab) {
#pragma unroll
    for (int r = 0; r < 4; ++r) {
      const int row = r * 32 + (tid >> 3);
      const int c8 = (tid & 7) ^ (row & 7);
      gload16(kslab + (size_t)row * NH + c8 * 8,
              smem + buf * 16384 + r * 4096 + wid * 1024);
    }
  };

  // MFMA compute for slab at compile-time ks (buf = ks), K-window ks*64..+64
  auto computeS = [&](int ks) {
    const char* kbuf = smem + ks * 16384;
#pragma unroll
    for (int k2 = 0; k2 < 2; ++k2) {
      bf16x8 B[8];
#pragma unroll
      for (int nb = 0; nb < 8; ++nb)
        B[nb] = *(const bf16x8*)(kbuf + (nb * 16 + l16) * 128 +
                                 (((k2 * 4 + lg) ^ (l16 & 7)) << 4));
      __builtin_amdgcn_s_setprio(1);
#pragma unroll
      for (int mb = 0; mb < 2; ++mb)
#pragma unroll
        for (int nb = 0; nb < 8; ++nb)
          sacc[mb][nb] = __builtin_amdgcn_mfma_f32_16x16x32_bf16(
              qA[mb][ks * 2 + k2], B[nb], sacc[mb][nb], 0, 0, 0);
      __builtin_amdgcn_s_setprio(0);
    }
  };

  const u16* kc = Kn + (size_t)dch * DCHUNK * NH;

  // prologue: slabs 0 (t0,h0)->buf0, 1 (t0,h64)->buf1
  stage_to(0, kc);
  stage_to(1, kc + 64);

  for (int t = 0; t < NDT; ++t) {
    const u16* ktile = kc + (size_t)t * 128 * NH;
#pragma unroll
    for (int mb = 0; mb < 2; ++mb)
#pragma unroll
      for (int nb = 0; nb < 8; ++nb) sacc[mb][nb] = f32x4{0.f, 0.f, 0.f, 0.f};

    // ks=0: issue slab 4t+2 = (t, h128) -> buf2
    stage_to(2, ktile + 128);
    VM8; SBAR;
    computeS(0);
    // ks=1: issue slab 4t+3 = (t, h192) -> buf3 (stash reads done: < bar ks0)
    stage_to(3, ktile + 192);
    VM8; SBAR;
    computeS(1);
    // ks=2: issue slab 4t+4 = (t+1, h0) -> buf0
    if (t < NDT - 1) { stage_to(0, ktile + 128 * NH); VM8; }
    else { VM4; }
    SBAR;
    computeS(2);
    // ks=3: issue slab 4t+5 = (t+1, h64) -> buf1
    if (t < NDT - 1) { stage_to(1, ktile + 128 * NH + 64); VM8; }
    else { VM0; }
    SBAR;
    computeS(3);

    // pre-PV barrier: all waves done reading buf3 (slab 4t+3) before stash
    SBAR;

    const int dbase = dch * DCHUNK + t * 128;
    char* sb = smem + 49152 + wid * 4096;  // buf3: [32 rows][128B], chunk^=row&7

#pragma unroll
    for (int half = 0; half < 2; ++half) {
      // cube (fp32) -> bf16 stash for this 64-d half
#pragma unroll
      for (int mb = 0; mb < 2; ++mb)
#pragma unroll
        for (int nb2 = 0; nb2 < 4; ++nb2) {
          f32x4 s = sacc[mb][half * 4 + nb2];
          f32x4 a3 = s * s * s;
#pragma unroll
          for (int r = 0; r < 4; ++r) {
            const int row = mb * 16 + lg * 4 + r;   // C/D: row=(lane>>4)*4+reg
            const int col = nb2 * 16 + l16;         //      col=lane&15 (in-half)
            *(u16*)(sb + row * 128 + (((col >> 3) ^ (row & 7)) << 4) +
                    (col & 7) * 2) = f2bf(a3[r]);
          }
        }

      // PV for this half: echo[q,c] += a[q,d] * Vt^T[d,c] (intensity = col 28)
#pragma unroll
      for (int mb = 0; mb < 2; ++mb) {
        const int arow = mb * 16 + l16;
#pragma unroll
        for (int dk = 0; dk < 2; ++dk) {
          const bf16x8 aA =
              *(const bf16x8*)(sb + arow * 128 + (((dk * 4 + lg) ^ (arow & 7)) << 4));
#pragma unroll
          for (int cn = 0; cn < 2; ++cn) {
            const bf16x8 vB = *(const bf16x8*)(Vt + (size_t)(cn * 16 + l16) * ND +
                                               dbase + half * 64 + dk * 32 + lg * 8);
            eacc[mb][cn] = __builtin_amdgcn_mfma_f32_16x16x32_bf16(
                aA, vB, eacc[mb][cn], 0, 0, 0);
          }
        }
      }
    }
    // no trailing barrier: next write to buf3 (slab 4t+7) is issued at ks=1
    // of t+1, i.e. after the ks=0 barrier, which orders all stash reads.
  }

  // ---- epilogue: write partials (slot = dch) ----
#pragma unroll
  for (int mb = 0; mb < 2; ++mb)
#pragma unroll
    for (int cn = 0; cn < 2; ++cn)
#pragma unroll
      for (int r = 0; r < 4; ++r) {
        const int row = rowbase + mb * 16 + lg * 4 + r;
        ep[((size_t)dch * NQ + row) * 32 + cn * 16 + l16] = eacc[mb][cn][r];
      }
}

// ---------------- reduce 16 partial slots -> d_out -------------------------
__global__ __launch_bounds__(256) void reduce_kernel(const float* __restrict__ ep,
                                                     float* __restrict__ out) {
  const int g = blockIdx.x * 256 + threadIdx.x;  // 8192*32
  const int q = g >> 5, c = g & 31;
  if (c < NC) {
    float s = 0.f;
#pragma unroll
    for (int k = 0; k < NSLOT; ++k) s += ep[((size_t)k * NQ + q) * 32 + c];
    out[(size_t)q * NC + c] = s;
  } else if (c == NC) {  // ones-column == intensity
    float s = 0.f;
#pragma unroll
    for (int k = 0; k < NSLOT; ++k) s += ep[((size_t)k * NQ + q) * 32 + NC];
    out[(size_t)NQ * NC + q] = s;
  }
}

extern "C" void kernel_launch(void* const* d_in, const int* in_sizes, int n_in,
                              void* d_out, int out_size, void* d_ws, size_t ws_size,
                              hipStream_t stream) {
  const float* feat = (const float*)d_in[0];  // [8192][256]
  const float* exf  = (const float*)d_in[1];  // [16384][256]
  const float* exc  = (const float*)d_in[2];  // [16384][28]
  float* out = (float*)d_out;
  char* ws = (char*)d_ws;
  // ws layout: qn 4MB | kn 8MB | vt 1MB | ep 16MB  (~29MB)
  u16* qn = (u16*)ws;
  u16* kn = (u16*)(ws + 4194304);
  u16* vt = (u16*)(ws + 12582912);
  float* ep = (float*)(ws + 13631488);

  norm_kernel<<<dim3(NQ / 4), dim3(256), 0, stream>>>(feat, qn, NQ);
  norm_kernel<<<dim3(ND / 4), dim3(256), 0, stream>>>(exf, kn, ND);
  vt_kernel<<<dim3(ND / 256), dim3(256), 0, stream>>>(exc, vt);
  fused_kernel<<<dim3(1024), dim3(256), 0, stream>>>(qn, kn, vt, ep);
  reduce_kernel<<<dim3(NQ * 32 / 256), dim3(256), 0, stream>>>(ep, out);
}

// Round 7
// 98.212 us; speedup vs baseline: 1.1138x; 1.1138x over previous
//
#include <hip/hip_runtime.h>
#include <stdint.h>

// minerva2: echo = (F̂ Ê^T)^3 @ V, intensity = rowsum((F̂ Ê^T)^3)
// R7 = R5 skeleton (32KB LDS, 2-buf, 4 barriers/tile) + swapped QK^T (S^T) +
// in-register cube/pack/permlane transpose -> PV A-frags. No LDS stash.

typedef unsigned short u16;
typedef __bf16 bf16x8 __attribute__((ext_vector_type(8)));
typedef float f32x4 __attribute__((ext_vector_type(4)));
typedef unsigned short u16x4 __attribute__((ext_vector_type(4)));

#define NQ 8192
#define ND 16384
#define NH 256
#define NC 28
#define DCHUNK 1024
#define NDT 8        // 128-row D-tiles per chunk
#define NSLOT 16     // partial slots = 16 D-chunks

__device__ __forceinline__ u16 f2bf(float f) {
  unsigned u = __builtin_bit_cast(unsigned, f);
  u += 0x7fffu + ((u >> 16) & 1u);   // RNE
  return (u16)(u >> 16);
}

__device__ __forceinline__ unsigned cvtpk(float lo, float hi) {
  unsigned r;
  asm("v_cvt_pk_bf16_f32 %0, %1, %2" : "=v"(r) : "v"(lo), "v"(hi));
  return r;  // low16 = bf16(lo), high16 = bf16(hi)  (RNE)
}

// After: x = [x.r0, x.r2, y.r0, y.r2] (by 16-lane row), y = [x.r1, x.r3, y.r1, y.r3]
__device__ __forceinline__ void swap2(unsigned& x, unsigned& y) {
  asm("v_permlane32_swap_b32 %0, %1" : "+v"(x), "+v"(y));  // x.r23 <-> y.r01
  asm("v_permlane16_swap_b32 %0, %1" : "+v"(x), "+v"(y));  // x.r1<->y.r0, x.r3<->y.r2
}

__device__ __forceinline__ void gload16(const void* g, void* l) {
  // async global->LDS, 16B/lane; LDS dest = wave-uniform base + lane*16
  __builtin_amdgcn_global_load_lds(
      (__attribute__((address_space(1))) void*)g,
      (__attribute__((address_space(3))) void*)l, 16, 0, 0);
}

// ---------------- normalize rows of [rows][256] f32 -> bf16 ----------------
__global__ __launch_bounds__(256) void norm_kernel(const float* __restrict__ in,
                                                   u16* __restrict__ out, int rows) {
  const int wid = threadIdx.x >> 6, lane = threadIdx.x & 63;
  const int row = blockIdx.x * 4 + wid;
  if (row >= rows) return;
  const float4* p = (const float4*)(in + (size_t)row * NH);
  float4 v = p[lane];
  float ss = v.x * v.x + v.y * v.y + v.z * v.z + v.w * v.w;
#pragma unroll
  for (int m = 1; m <= 32; m <<= 1) ss += __shfl_xor(ss, m, 64);
  const float sc = 1.0f / fmaxf(sqrtf(ss), 1e-12f);  // matches F.normalize eps
  u16x4 o;
  o.x = f2bf(v.x * sc); o.y = f2bf(v.y * sc);
  o.z = f2bf(v.z * sc); o.w = f2bf(v.w * sc);
  *(u16x4*)(out + (size_t)row * NH + lane * 4) = o;
}

// ---- V [16384][28] f32 -> Vt [32][16384] bf16; col 28 = 1.0 (intensity) ---
__global__ __launch_bounds__(256) void vt_kernel(const float* __restrict__ V,
                                                 u16* __restrict__ Vt) {
  const int d = blockIdx.x * 256 + threadIdx.x;  // 16384
#pragma unroll
  for (int c = 0; c < NC; ++c) Vt[(size_t)c * ND + d] = f2bf(V[(size_t)d * NC + c]);
  Vt[(size_t)28 * ND + d] = 0x3F80;  // bf16 1.0 -> echo col 28 == intensity
  Vt[(size_t)29 * ND + d] = 0;
  Vt[(size_t)30 * ND + d] = 0;
  Vt[(size_t)31 * ND + d] = 0;
}

// ---------------- fused main kernel ----------------------------------------
// grid 1024: dch = bid&15 (XCD-local), ntile = bid>>4. 4 waves, 1x4 over q:
// wave w owns q-rows [ntile*128+w*32, +32) x 128 d-cols per tile.
// Q in registers. LDS 32KB: K slab dbuf (2 x 16KB). No stash (in-reg transpose).
// QK^T computed SWAPPED: sacc[mb][nb] = S^T tile, lane: q=l16, d=lg*4+r.
__global__ __launch_bounds__(256, 2) void fused_kernel(
    const u16* __restrict__ Qn, const u16* __restrict__ Kn,
    const u16* __restrict__ Vt, float* __restrict__ ep) {
  __shared__ alignas(16) char smem[32768];
  const int tid = threadIdx.x;
  const int wid = tid >> 6;
  const int lane = tid & 63;
  const int l16 = lane & 15;
  const int lg = lane >> 4;
  const int dch = blockIdx.x & 15;
  const int ntile = blockIdx.x >> 4;
  const int qbase = ntile * 128;
  const int rowbase = qbase + wid * 32;

  // ---- Q fragments, all H, in registers (used as the MFMA B-operand) ----
  bf16x8 qA[2][8];
#pragma unroll
  for (int mb = 0; mb < 2; ++mb)
#pragma unroll
    for (int ks = 0; ks < 8; ++ks)
      qA[mb][ks] = *(const bf16x8*)(Qn + (size_t)(rowbase + mb * 16 + l16) * NH +
                                    ks * 32 + lg * 8);

  f32x4 eacc[2][2];
#pragma unroll
  for (int mb = 0; mb < 2; ++mb) {
    eacc[mb][0] = f32x4{0.f, 0.f, 0.f, 0.f};
    eacc[mb][1] = f32x4{0.f, 0.f, 0.f, 0.f};
  }
  f32x4 sacc[2][8];

  // stage one 64-wide H-slab of the K-tile (128 rows) into buf.
  // Linear LDS dest; source chunk pre-swizzled: c8 ^= row&7 (rule #21).
  auto stageK = [&](int buf, int h0, const u16* kt) {
#pragma unroll
    for (int r = 0; r < 4; ++r) {
      const int row = r * 32 + (tid >> 3);
      const int c8 = (tid & 7) ^ (row & 7);
      gload16(kt + (size_t)row * NH + h0 + c8 * 8,
              smem + buf * 16384 + r * 4096 + wid * 1024);
    }
  };

  const u16* kc = Kn + (size_t)dch * DCHUNK * NH;
  stageK(0, 0, kc);
  __syncthreads();

  for (int t = 0; t < NDT; ++t) {
    const u16* kt = kc + (size_t)t * 128 * NH;
#pragma unroll
    for (int mb = 0; mb < 2; ++mb)
#pragma unroll
      for (int nb = 0; nb < 8; ++nb) sacc[mb][nb] = f32x4{0.f, 0.f, 0.f, 0.f};

#pragma unroll
    for (int ks = 0; ks < 4; ++ks) {
      if (ks < 3) stageK((ks + 1) & 1, (ks + 1) * 64, kt);
      else if (t < NDT - 1) stageK(0, 0, kt + 128 * NH);  // next-t slab0 -> buf0
      const char* kbuf = smem + (ks & 1) * 16384;
#pragma unroll
      for (int k2 = 0; k2 < 2; ++k2) {
        bf16x8 B[8];
#pragma unroll
        for (int nb = 0; nb < 8; ++nb)
          B[nb] = *(const bf16x8*)(kbuf + (nb * 16 + l16) * 128 +
                                   (((k2 * 4 + lg) ^ (l16 & 7)) << 4));
        // SWAPPED: A = K-frag (d rows), B = Q-frag (q cols) -> D = S^T
#pragma unroll
        for (int mb = 0; mb < 2; ++mb)
#pragma unroll
          for (int nb = 0; nb < 8; ++nb)
            sacc[mb][nb] = __builtin_amdgcn_mfma_f32_16x16x32_bf16(
                B[nb], qA[mb][ks * 2 + k2], sacc[mb][nb], 0, 0, 0);
      }
      __syncthreads();
    }

    // ---- cube (fp32) -> bf16 pack -> permlane transpose -> PV MFMA ----
    // sacc[mb][nb]: q = l16, d(in tile) = nb*16 + lg*4 + r.
    // PV A-frag needs q = l16 (ok), k = lg*8+i covering 32-d group tg.
    const int dbase = dch * DCHUNK + t * 128;
#pragma unroll
    for (int mb = 0; mb < 2; ++mb) {
#pragma unroll
      for (int tg = 0; tg < 4; ++tg) {
        f32x4 sx = sacc[mb][2 * tg];
        f32x4 sy = sacc[mb][2 * tg + 1];
        f32x4 cx = sx * sx * sx;
        f32x4 cy = sy * sy * sy;
        unsigned x0 = cvtpk(cx[0], cx[1]);  // d = 4lg+0,1   (nb = 2tg)
        unsigned x1 = cvtpk(cx[2], cx[3]);  // d = 4lg+2,3
        unsigned y0 = cvtpk(cy[0], cy[1]);  // same, nb = 2tg+1
        unsigned y1 = cvtpk(cy[2], cy[3]);
        swap2(x0, y0);  // x0 -> a0 (k 8g+0,1), y0 -> a2 (k 8g+4,5)
        swap2(x1, y1);  // x1 -> a1 (k 8g+2,3), y1 -> a3 (k 8g+6,7)
        const int4 ai = {(int)x0, (int)x1, (int)y0, (int)y1};
        const bf16x8 aA = __builtin_bit_cast(bf16x8, ai);
#pragma unroll
        for (int cn = 0; cn < 2; ++cn) {
          const bf16x8 vBf = *(const bf16x8*)(Vt + (size_t)(cn * 16 + l16) * ND +
                                              dbase + tg * 32 + lg * 8);
          eacc[mb][cn] = __builtin_amdgcn_mfma_f32_16x16x32_bf16(
              aA, vBf, eacc[mb][cn], 0, 0, 0);
        }
      }
    }
    // no barrier needed: PV touches no LDS; K bufs protected by ks-loop barriers
  }

  // ---- epilogue: write partials (slot = dch) ----
#pragma unroll
  for (int mb = 0; mb < 2; ++mb)
#pragma unroll
    for (int cn = 0; cn < 2; ++cn)
#pragma unroll
      for (int r = 0; r < 4; ++r) {
        const int row = rowbase + mb * 16 + lg * 4 + r;
        ep[((size_t)dch * NQ + row) * 32 + cn * 16 + l16] = eacc[mb][cn][r];
      }
}

// ---------------- reduce 16 partial slots -> d_out -------------------------
__global__ __launch_bounds__(256) void reduce_kernel(const float* __restrict__ ep,
                                                     float* __restrict__ out) {
  const int g = blockIdx.x * 256 + threadIdx.x;  // 8192*32
  const int q = g >> 5, c = g & 31;
  if (c < NC) {
    float s = 0.f;
#pragma unroll
    for (int k = 0; k < NSLOT; ++k) s += ep[((size_t)k * NQ + q) * 32 + c];
    out[(size_t)q * NC + c] = s;
  } else if (c == NC) {  // ones-column == intensity
    float s = 0.f;
#pragma unroll
    for (int k = 0; k < NSLOT; ++k) s += ep[((size_t)k * NQ + q) * 32 + NC];
    out[(size_t)NQ * NC + q] = s;
  }
}

extern "C" void kernel_launch(void* const* d_in, const int* in_sizes, int n_in,
                              void* d_out, int out_size, void* d_ws, size_t ws_size,
                              hipStream_t stream) {
  const float* feat = (const float*)d_in[0];  // [8192][256]
  const float* exf  = (const float*)d_in[1];  // [16384][256]
  const float* exc  = (const float*)d_in[2];  // [16384][28]
  float* out = (float*)d_out;
  char* ws = (char*)d_ws;
  // ws layout: qn 4MB | kn 8MB | vt 1MB | ep 16MB  (~29MB)
  u16* qn = (u16*)ws;
  u16* kn = (u16*)(ws + 4194304);
  u16* vt = (u16*)(ws + 12582912);
  float* ep = (float*)(ws + 13631488);

  norm_kernel<<<dim3(NQ / 4), dim3(256), 0, stream>>>(feat, qn, NQ);
  norm_kernel<<<dim3(ND / 4), dim3(256), 0, stream>>>(exf, kn, ND);
  vt_kernel<<<dim3(ND / 256), dim3(256), 0, stream>>>(exc, vt);
  fused_kernel<<<dim3(1024), dim3(256), 0, stream>>>(qn, kn, vt, ep);
  reduce_kernel<<<dim3(NQ * 32 / 256), dim3(256), 0, stream>>>(ep, out);
}